// Round 6
// baseline (255.961 us; speedup 1.0000x reference)
//
#include <hip/hip_runtime.h>

// ---------------------------------------------------------------------------
// GaussianDiffusionTrainer forward, split in two:
//   K1 (scale):  out[b,c,h,w] = x0[b,c,h,w] * P[t_b-1]        (pure f4 stream)
//   K2 (diag):   out[b,c,k,k] += nrm[b,c,k,k] * C[t_b-1]      (786K scalar RMW)
// (8192, 3, 32, 32) fp32.  P,C = compile-time constexpr tables.
//
// R4 -> R5/R6: the divergent diagonal gather inside the streaming loop's
// dependent chain was the latency poison (R2/R4 both ~2 TB/s). K1 is now
// structurally identical to the 6.3 TB/s float4 copy: blockIdx/3 is
// wave-uniform -> tsteps/P lookups compile to s_loads off the vector path.
// ---------------------------------------------------------------------------

constexpr int T_STEPS = 1000;
constexpr int BATCH   = 8192;
constexpr int K1_BLOCKS  = BATCH * 3;            // 24576: each block = 256 f4
constexpr int N_DIAG     = BATCH * 3 * 32;       // 786432 diagonal elements
constexpr int K2_BLOCKS  = N_DIAG / 256;         // 3072

struct Tables { float P[T_STEPS]; float C[T_STEPS]; };

constexpr double csqrt_d(double x) {
    if (x <= 0.0) return 0.0;
    double scale = 1.0;
    while (x < 0.25) { x *= 4.0;  scale *= 0.5; }
    while (x >= 1.0) { x *= 0.25; scale *= 2.0; }
    double g = 0.5 * (x + 1.0);
    for (int i = 0; i < 40; ++i) {
        double ng = 0.5 * (g + x / g);
        if (ng == g) break;
        g = ng;
    }
    return g * scale;   // scale is a power of two -> exact
}

constexpr Tables make_tables() {
    Tables t{};
    const float beta1 = 1e-4f;
    const float betaT = 0.02f;
    const float delta = (betaT - beta1) / 1000.0f;
    float ac = 1.0f, P = 1.0f, c = 0.0f;
    for (int k = 0; k < T_STEPS; ++k) {
        float beta = beta1 + (float)k * delta;
        ac = ac * (1.0f - beta);
        float s = (float)csqrt_d((double)ac);
        P = P * s;
        c = c * s + beta * beta;
        t.P[k] = P;
        t.C[k] = c;
    }
    return t;
}

__device__ __constant__ Tables d_tbl = make_tables();

// K1: pure scale stream. One block = 256 float4 = 1/3 image, so the image
// index (blockIdx.x / 3) is uniform -> coefficient lookups are scalar loads.
__global__ __launch_bounds__(256) void scale_kernel(
    const float* __restrict__ x0,
    const int*   __restrict__ tsteps,
    float*       __restrict__ out)
{
    const int bid = blockIdx.x;
    const int img = bid / 3;                     // wave-uniform
    const int t   = tsteps[img] - 1;             // s_load
    const float Pt = d_tbl.P[t];                 // s_load (constant mem)

    const int f = bid * 256 + threadIdx.x;
    const float4 x = reinterpret_cast<const float4*>(x0)[f];
    float4 r;
    r.x = x.x * Pt;
    r.y = x.y * Pt;
    r.z = x.z * Pt;
    r.w = x.w * Pt;
    reinterpret_cast<float4*>(out)[f] = r;
}

// K2: diagonal fix-up. One thread per diagonal element (b,c,k,k).
__global__ __launch_bounds__(256) void diag_kernel(
    const float* __restrict__ nrm,
    const int*   __restrict__ tsteps,
    float*       __restrict__ out)
{
    const int gid = blockIdx.x * 256 + threadIdx.x;   // 0 .. N_DIAG-1
    const int img = gid / 96;                          // 96 diag elems / image
    const int rem = gid - img * 96;                    // c*32 + k
    const int off = img * 3072 + rem * 32 + (rem & 31);// c*1024 + k*33

    const int t    = tsteps[img] - 1;
    const float Ct = d_tbl.C[t];

    out[off] = fmaf(nrm[off], Ct, out[off]);
}

extern "C" void kernel_launch(void* const* d_in, const int* in_sizes, int n_in,
                              void* d_out, int out_size, void* d_ws, size_t ws_size,
                              hipStream_t stream) {
    const float* x0     = (const float*)d_in[0];
    const float* nrm    = (const float*)d_in[1];
    const int*   tsteps = (const int*)d_in[2];
    float*       out    = (float*)d_out;

    scale_kernel<<<K1_BLOCKS, 256, 0, stream>>>(x0, tsteps, out);
    diag_kernel <<<K2_BLOCKS, 256, 0, stream>>>(nrm, tsteps, out);
}

// Round 9
// 242.399 us; speedup vs baseline: 1.0559x; 1.0559x over previous
//
#include <hip/hip_runtime.h>

// ---------------------------------------------------------------------------
// GaussianDiffusionTrainer forward (fused; scalar coeffs + 3-deep MLP):
//   x_t[b,c,h,w] = x0[b,c,h,w] * P[t_b-1] + (h==w ? normal[b,c,h,w] * C[t_b-1] : 0)
// (8192, 3, 32, 32) fp32.  P,C = compile-time constexpr tables.
//
// R8 -> R9 (hedged: fixes BOTH candidate limiters at once):
//  (a) scalar coefficient path: one block = one image -> img = blockIdx.x,
//      readfirstlane(tsteps[img]) -> P/C are s_loads, once per wave.
//  (b) memory-level parallelism: each thread owns 3 float4s (one per
//      channel), loaded into named registers up front -> 3+ independent
//      VMEM ops in flight per lane instead of one dependent chain.
// Within-channel f4 index == tid, so diagonal geometry is computed once.
// ---------------------------------------------------------------------------

constexpr int T_STEPS = 1000;
constexpr int BATCH   = 8192;
constexpr int BLOCKS  = BATCH;       // one block per image (768 f4 / image)

struct Tables { float P[T_STEPS]; float C[T_STEPS]; };

constexpr double csqrt_d(double x) {
    if (x <= 0.0) return 0.0;
    double scale = 1.0;
    while (x < 0.25) { x *= 4.0;  scale *= 0.5; }
    while (x >= 1.0) { x *= 0.25; scale *= 2.0; }
    double g = 0.5 * (x + 1.0);
    for (int i = 0; i < 40; ++i) {
        double ng = 0.5 * (g + x / g);
        if (ng == g) break;
        g = ng;
    }
    return g * scale;   // scale is a power of two -> exact
}

constexpr Tables make_tables() {
    Tables t{};
    const float beta1 = 1e-4f;
    const float betaT = 0.02f;
    const float delta = (betaT - beta1) / 1000.0f;
    float ac = 1.0f, P = 1.0f, c = 0.0f;
    for (int k = 0; k < T_STEPS; ++k) {
        float beta = beta1 + (float)k * delta;
        ac = ac * (1.0f - beta);
        float s = (float)csqrt_d((double)ac);
        P = P * s;
        c = c * s + beta * beta;
        t.P[k] = P;
        t.C[k] = c;
    }
    return t;
}

__device__ __constant__ Tables d_tbl = make_tables();

__global__ __launch_bounds__(256) void gd_fused_kernel(
    const float* __restrict__ x0,
    const float* __restrict__ nrm,
    const int*   __restrict__ tsteps,
    float*       __restrict__ out)
{
    const int img = blockIdx.x;                            // wave-uniform
    const int t   = __builtin_amdgcn_readfirstlane(tsteps[img] - 1);
    const float Pt = d_tbl.P[t];                           // s_load (constant)
    const float Ct = d_tbl.C[t];                           // s_load (constant)

    const int tid = threadIdx.x;
    // Within-channel geometry (f4 index within channel == tid):
    const int h  = tid >> 3;            // row 0..31
    const int w0 = (tid & 7) << 2;      // first col of this float4
    const int d  = h - w0;              // diag component if 0 <= d < 4
    const bool has_diag = (unsigned)d < 4u;

    const int f0 = img * 768 + tid;     // channel 0 f4 index
    const float4* __restrict__ x4 = reinterpret_cast<const float4*>(x0);
    float4*       __restrict__ o4 = reinterpret_cast<float4*>(out);

    // Issue all loads up front — 3 (+3) independent VMEM ops in flight.
    const float4 xa = x4[f0];
    const float4 xb = x4[f0 + 256];
    const float4 xc = x4[f0 + 512];

    float na = 0.0f, nb = 0.0f, nc = 0.0f;
    if (has_diag) {
        na = nrm[((f0      ) << 2) + d];
        nb = nrm[((f0 + 256) << 2) + d];
        nc = nrm[((f0 + 512) << 2) + d];
    }

    float4 r;
    r.x = xa.x * Pt + (d == 0 ? na * Ct : 0.0f);
    r.y = xa.y * Pt + (d == 1 ? na * Ct : 0.0f);
    r.z = xa.z * Pt + (d == 2 ? na * Ct : 0.0f);
    r.w = xa.w * Pt + (d == 3 ? na * Ct : 0.0f);
    o4[f0] = r;

    r.x = xb.x * Pt + (d == 0 ? nb * Ct : 0.0f);
    r.y = xb.y * Pt + (d == 1 ? nb * Ct : 0.0f);
    r.z = xb.z * Pt + (d == 2 ? nb * Ct : 0.0f);
    r.w = xb.w * Pt + (d == 3 ? nb * Ct : 0.0f);
    o4[f0 + 256] = r;

    r.x = xc.x * Pt + (d == 0 ? nc * Ct : 0.0f);
    r.y = xc.y * Pt + (d == 1 ? nc * Ct : 0.0f);
    r.z = xc.z * Pt + (d == 2 ? nc * Ct : 0.0f);
    r.w = xc.w * Pt + (d == 3 ? nc * Ct : 0.0f);
    o4[f0 + 512] = r;
}

extern "C" void kernel_launch(void* const* d_in, const int* in_sizes, int n_in,
                              void* d_out, int out_size, void* d_ws, size_t ws_size,
                              hipStream_t stream) {
    const float* x0     = (const float*)d_in[0];
    const float* nrm    = (const float*)d_in[1];
    const int*   tsteps = (const int*)d_in[2];
    float*       out    = (float*)d_out;

    gd_fused_kernel<<<BLOCKS, 256, 0, stream>>>(x0, nrm, tsteps, out);
}